// Round 1
// 516.175 us; speedup vs baseline: 1.0992x; 1.0992x over previous
//
#include <hip/hip_runtime.h>
#include <cmath>
#include <cstdint>

#define NROWS 65536
#define DIMN  256
#define NRF   256
#define OUTD  1024
#define KDIM  1024   // 4*NRF
#define MCOEF 0.001f

typedef __bf16 v8bf __attribute__((ext_vector_type(8)));
typedef float  v4f  __attribute__((ext_vector_type(4)));
typedef unsigned short us8 __attribute__((ext_vector_type(8)));

__device__ __forceinline__ unsigned short f2bf(float f) {
  unsigned int u = __float_as_uint(f);
  u += 0x7fffu + ((u >> 16) & 1u);   // round-to-nearest-even
  return (unsigned short)(u >> 16);
}

__device__ __forceinline__ void async_copy16(const void* g, void* l) {
  __builtin_amdgcn_global_load_lds(
      (const __attribute__((address_space(1))) void*)g,
      (__attribute__((address_space(3))) void*)l, 16, 0, 0);
}

// XOR-swizzled tile layout (breaks the 8-way bank conflict of row-stride-64B):
//   LDS slot idx (16B granules) holds global 8-elem chunk ((idx&3)^((idx>>3)&3))
//   of row (idx>>2). Reader: row r, chunk c -> slot 4r + ((c ^ (r>>1)) & 3).
__device__ __forceinline__ int sw_slot(int r, int c) {
  return r * 4 + ((c ^ (r >> 1)) & 3);
}

// proj -> bf16, and mg2[i] = M * ||proj_i||^2 (fp32)
__global__ __launch_bounds__(64) void prep_rf(
    const float* __restrict__ proj, unsigned short* __restrict__ projbf,
    float* __restrict__ mg2) {
  int i = blockIdx.x;
  int lane = threadIdx.x;  // 64 threads
  float4 v = ((const float4*)(proj + (size_t)i * DIMN))[lane];
  ushort4 o;
  o.x = f2bf(v.x); o.y = f2bf(v.y); o.z = f2bf(v.z); o.w = f2bf(v.w);
  ((ushort4*)(projbf + (size_t)i * DIMN))[lane] = o;
  float ss = v.x * v.x + v.y * v.y + v.z * v.z + v.w * v.w;
#pragma unroll
  for (int off = 32; off > 0; off >>= 1) ss += __shfl_down(ss, off, 64);
  if (lane == 0) mg2[i] = MCOEF * ss;
}

// Fused feature kernel for BOTH x (blocks 16..1039) and weights (blocks 0..15).
// K layout is INTERLEAVED: column k = 4*rf + component, identical for F and Wp,
// so the downstream gemm (sum over k) is unchanged but the epilogue writes one
// aligned ds_write_b64 per accumulator element instead of 4x ds_write_b16.
__global__ __launch_bounds__(256) void fused_features(
    const float* __restrict__ srcX,          // 65536 x 256 fp32
    const float* __restrict__ srcW,          // 1024 x 256 fp32
    const float* __restrict__ biasW,         // raw b (scaled by 0.25 here)
    const float* __restrict__ xr_g, const float* __restrict__ xi_g,
    const float* __restrict__ mg2_g,
    const unsigned short* __restrict__ projbf,  // 256 x 256 bf16
    unsigned short* __restrict__ FX,         // 65536 x 1024 bf16
    unsigned short* __restrict__ FW,         // 1024 x 1024 bf16
    float sRx, float sRw, float scaleC) {
  // 32 KB union: K-loop uses As(4K)+Bs(16K); epilogue reuses all as Os(32K)
  __shared__ __align__(16) unsigned short big[16 * 1024];
  unsigned short* As = big;          // 64 rows x 32 k (swizzled slots)
  unsigned short* Bs = big + 2048;   // 256 rows x 32 k (swizzled slots)
  unsigned short* Os = big;          // 16 rows x 1024 cols
  __shared__ float xr_s[256], xi_s[256], c1_s[256], c2_s[256], mg2_s[256];
  __shared__ float sq_s[64], bias_s[64];

  int t = threadIdx.x;
  int lane = t & 63;
  int w = t >> 6;

  bool isW = blockIdx.x < (OUTD / 64);
  int blockRow = isW ? blockIdx.x * 64 : (blockIdx.x - OUTD / 64) * 64;
  const float* src = isW ? srcW : srcX;
  float scl = isW ? 0.25f : (1.f / DIMN);
  unsigned short* Fout = isW ? FW : FX;
  float sR = isW ? sRw : sRx;
  float sI = isW ? -sRw : sRx;

  {
    float a = xr_g[t], b = xi_g[t];
    xr_s[t] = a; xi_s[t] = b;
    c1_s[t] = a * a - b * b;   // Re(z^2)
    c2_s[t] = 2.f * a * b;     // Im(z^2)
    mg2_s[t] = mg2_g[t];
  }
  if (t < 64) bias_s[t] = isW ? biasW[blockRow + t] * 0.25f : 0.f;

  v4f acc[4][4];
#pragma unroll
  for (int a = 0; a < 4; a++)
#pragma unroll
    for (int b = 0; b < 4; b++)
#pragma unroll
      for (int q = 0; q < 4; q++) acc[a][b][q] = 0.f;

  // each thread owns 8 k-columns of one A row: row = t>>2, chunk sub
  int arow = t >> 2, sub = t & 3;
  const float* srow = src + (size_t)(blockRow + arow) * DIMN + sub * 8;
  float ss = 0.f;

  for (int kb = 0; kb < DIMN; kb += 32) {
    // A: fp32 load -> scale -> bf16 -> LDS swizzled slot (+ sum of squares)
    float4 v0 = *(const float4*)(srow + kb);
    float4 v1 = *(const float4*)(srow + kb + 4);
    v0.x *= scl; v0.y *= scl; v0.z *= scl; v0.w *= scl;
    v1.x *= scl; v1.y *= scl; v1.z *= scl; v1.w *= scl;
    ss += v0.x * v0.x + v0.y * v0.y + v0.z * v0.z + v0.w * v0.w +
          v1.x * v1.x + v1.y * v1.y + v1.z * v1.z + v1.w * v1.w;
    us8 o;
    o[0] = f2bf(v0.x); o[1] = f2bf(v0.y); o[2] = f2bf(v0.z); o[3] = f2bf(v0.w);
    o[4] = f2bf(v1.x); o[5] = f2bf(v1.y); o[6] = f2bf(v1.z); o[7] = f2bf(v1.w);
    *(us8*)&As[sw_slot(arow, sub) * 8] = o;
    // B: 256x32 tile = 16 KB via global_load_lds, source-chunk swizzled
#pragma unroll
    for (int r = 0; r < 4; r++) {
      int idx = r * 256 + t;
      int row = idx >> 2, kc = ((idx & 3) ^ ((idx >> 3) & 3)) * 8;
      async_copy16(projbf + (size_t)row * DIMN + kb + kc,
                   Bs + (idx & ~63) * 8);
    }
    __syncthreads();
    v8bf af[4], bfv[4];
    int c = lane >> 4;
#pragma unroll
    for (int mi = 0; mi < 4; mi++)
      af[mi] = *(const v8bf*)&As[sw_slot(mi * 16 + (lane & 15), c) * 8];
#pragma unroll
    for (int ni = 0; ni < 4; ni++)
      bfv[ni] = *(const v8bf*)&Bs[sw_slot(w * 64 + ni * 16 + (lane & 15), c) * 8];
#pragma unroll
    for (int mi = 0; mi < 4; mi++)
#pragma unroll
      for (int ni = 0; ni < 4; ni++)
        acc[mi][ni] = __builtin_amdgcn_mfma_f32_16x16x32_bf16(
            af[mi], bfv[ni], acc[mi][ni], 0, 0, 0);
    __syncthreads();
  }

  // row sum-of-squares: reduce the 4 sub-threads of each row
  ss += __shfl_xor(ss, 1, 64);
  ss += __shfl_xor(ss, 2, 64);
  if (sub == 0) sq_s[arow] = ss;

#pragma unroll
  for (int mi = 0; mi < 4; mi++) {
    __syncthreads();   // Os (=As/Bs space) free to overwrite; sq_s visible
#pragma unroll
    for (int ni = 0; ni < 4; ni++) {
      int i = w * 64 + ni * 16 + (lane & 15);  // rf index
      float xrv = xr_s[i], xiv = xi_s[i];
      float c1v = c1_s[i], c2v = c2_s[i], mgv = mg2_s[i];
#pragma unroll
      for (int reg = 0; reg < 4; reg++) {
        int rl    = (lane >> 4) * 4 + reg;       // row within 16-row mi-tile
        int rglob = mi * 16 + rl;                // row within block
        float px = acc[mi][ni][reg];
        float tt = scaleC * px + bias_s[rglob];
        float u  = 0.5f * sq_s[rglob];
        float aa = u * c1v + mgv;
        float bb = u * c2v;
        float txr = tt * xrv;
        float txi = tt * xiv;
        float erp = __expf(txr - aa);
        float erm = __expf(-txr - aa);
        float s1, cc1, s2, cc2;
        __sincosf(txi - bb, &s1, &cc1);
        __sincosf(txi + bb, &s2, &cc2);
        ushort4 ov;
        ov.x = f2bf(sR * erp * cc1);
        ov.y = f2bf(sR * erm * cc2);
        ov.z = f2bf(sI * erp * s1);
        ov.w = f2bf(-sI * erm * s2);
        // interleaved K layout: columns 4*i .. 4*i+3, one 8B write
        *(ushort4*)&Os[rl * KDIM + 4 * i] = ov;
      }
    }
    __syncthreads();
    // stream 16 rows x 1024 cols bf16 = 32 KB, 16 B per lane, coalesced
#pragma unroll
    for (int j = 0; j < 8; j++) {
      int chunk = j * 256 + t;          // 2048 chunks of 8 shorts
      int rowo  = chunk >> 7;           // 0..15
      int off   = (chunk & 127) * 8;    // 0..1016
      *(us8*)(Fout + (size_t)(blockRow + mi * 16 + rowo) * KDIM + off) =
          *(const us8*)&Os[rowo * KDIM + off];
    }
  }
}

// out[n,o] = sum_k A[n,k]*B[o,k]; 128x128 tile, BK=32, swizzled LDS,
// XCD-aware block mapping, 2-phase double-buffered prefetch (T3-minimum):
// next tile's global_load_lds issued BEFORE computing current tile, one
// vmcnt(0)+barrier per K-step so loads fly under ds_read+MFMA.
__global__ __launch_bounds__(256) void gemm_bt(
    const unsigned short* __restrict__ A,   // NROWS x KDIM bf16
    const unsigned short* __restrict__ B,   // OUTD x KDIM bf16
    float* __restrict__ C) {                // NROWS x OUTD fp32
  __shared__ __align__(16) unsigned short As[2][128 * 32];
  __shared__ __align__(16) unsigned short Bs[2][128 * 32];
  int t = threadIdx.x;
  int lane = t & 63;
  int w = t >> 6;
  int wm = w >> 1, wn = w & 1;
  int lid = blockIdx.x;
  int slot = lid >> 3;                      // 0..511
  size_t bm = (size_t)(((lid & 7) * 64) + (slot >> 3)) * 128;  // row panel
  size_t bn = (size_t)(slot & 7) * 128;                        // col panel

  v4f acc[4][4];
#pragma unroll
  for (int a = 0; a < 4; a++)
#pragma unroll
    for (int b = 0; b < 4; b++)
#pragma unroll
      for (int q = 0; q < 4; q++) acc[a][b][q] = 0.f;

  auto stage = [&](int buf, int kb) {
#pragma unroll
    for (int r = 0; r < 2; r++) {
      int idx = r * 256 + t;
      int row = idx >> 2, kc = ((idx & 3) ^ ((idx >> 3) & 3)) * 8;
      async_copy16(A + (bm + row) * KDIM + kb + kc, &As[buf][(idx & ~63) * 8]);
      async_copy16(B + (bn + row) * KDIM + kb + kc, &Bs[buf][(idx & ~63) * 8]);
    }
  };

  auto compute_tile = [&](int buf) {
    v8bf af[4], bfv[4];
    int c = lane >> 4;
#pragma unroll
    for (int mi = 0; mi < 4; mi++)
      af[mi] = *(const v8bf*)&As[buf][sw_slot(wm * 64 + mi * 16 + (lane & 15), c) * 8];
#pragma unroll
    for (int ni = 0; ni < 4; ni++)
      bfv[ni] = *(const v8bf*)&Bs[buf][sw_slot(wn * 64 + ni * 16 + (lane & 15), c) * 8];
#pragma unroll
    for (int mi = 0; mi < 4; mi++)
#pragma unroll
      for (int ni = 0; ni < 4; ni++)
        acc[mi][ni] = __builtin_amdgcn_mfma_f32_16x16x32_bf16(
            af[mi], bfv[ni], acc[mi][ni], 0, 0, 0);
  };

  stage(0, 0);
  asm volatile("s_waitcnt vmcnt(0)" ::: "memory");
  __syncthreads();
  int cur = 0;
  for (int kb = 32; kb < KDIM; kb += 32) {
    stage(cur ^ 1, kb);      // prefetch next tile (in flight during compute)
    compute_tile(cur);
    asm volatile("s_waitcnt vmcnt(0)" ::: "memory");
    __syncthreads();         // next buffer staged; everyone done reading cur
    cur ^= 1;
  }
  compute_tile(cur);

#pragma unroll
  for (int mi = 0; mi < 4; mi++)
#pragma unroll
    for (int ni = 0; ni < 4; ni++)
#pragma unroll
      for (int reg = 0; reg < 4; reg++) {
        size_t row = bm + wm * 64 + mi * 16 + (lane >> 4) * 4 + reg;
        size_t col = bn + wn * 64 + ni * 16 + (lane & 15);
        C[row * OUTD + col] = acc[mi][ni][reg];
      }
}

extern "C" void kernel_launch(void* const* d_in, const int* in_sizes, int n_in,
                              void* d_out, int out_size, void* d_ws, size_t ws_size,
                              hipStream_t stream) {
  (void)in_sizes; (void)n_in; (void)out_size;
  const float* x    = (const float*)d_in[0];
  const float* iw   = (const float*)d_in[1];
  const float* bvec = (const float*)d_in[2];
  const float* proj = (const float*)d_in[3];
  const float* xr   = (const float*)d_in[4];
  const float* xi   = (const float*)d_in[5];
  float* out = (float*)d_out;

  char* ws = (char*)d_ws;
  size_t off = 0;
  auto take = [&](size_t bytes) {
    char* p = ws + off;
    off = (off + bytes + 255) & ~(size_t)255;
    return p;
  };
  unsigned short* F      = (unsigned short*)take((size_t)NROWS * KDIM * 2);  // 134 MB
  unsigned short* Wp     = (unsigned short*)take((size_t)OUTD * KDIM * 2);   // 2 MB
  unsigned short* projbf = (unsigned short*)take((size_t)NRF * DIMN * 2);    // 128 KB
  float* mg2 = (float*)take((size_t)NRF * 4);
  if (ws_size < off) return;  // workspace too small: bail cleanly (diagnosable)

  const float  scaleC = sqrtf(1.f + 4.f * MCOEF);                 // sqrt(1.004)
  const double c2d    = 0.5 * exp(128.0 * log(1.0 + 4.0 * 0.001));// c^2
  const float  invSR  = 0.0625f;                                   // 1/sqrt(256)
  const float  sRw    = (float)(c2d * 0.0625);

  prep_rf<<<NRF, 64, 0, stream>>>(proj, projbf, mg2);
  // blocks 0..15 = weight rows (start early, overlap with x blocks);
  // blocks 16..1039 = x rows
  fused_features<<<NROWS / 64 + OUTD / 64, 256, 0, stream>>>(
      x, iw, bvec, xr, xi, mg2, projbf, F, Wp, invSR, sRw, scaleC);
  gemm_bt<<<4096, 256, 0, stream>>>(F, Wp, out);
}

// Round 2
// 506.840 us; speedup vs baseline: 1.1194x; 1.0184x over previous
//
#include <hip/hip_runtime.h>
#include <cmath>
#include <cstdint>

#define NROWS 65536
#define DIMN  256
#define NRF   256
#define OUTD  1024
#define KDIM  1024   // 4*NRF
#define MCOEF 0.001f

typedef __bf16 v8bf __attribute__((ext_vector_type(8)));
typedef float  v4f  __attribute__((ext_vector_type(4)));
typedef unsigned short us8 __attribute__((ext_vector_type(8)));

__device__ __forceinline__ unsigned short f2bf(float f) {
  unsigned int u = __float_as_uint(f);
  u += 0x7fffu + ((u >> 16) & 1u);   // round-to-nearest-even
  return (unsigned short)(u >> 16);
}

__device__ __forceinline__ void async_copy16(const void* g, void* l) {
  __builtin_amdgcn_global_load_lds(
      (const __attribute__((address_space(1))) void*)g,
      (__attribute__((address_space(3))) void*)l, 16, 0, 0);
}

// XOR-swizzled tile layout for the feature kernel (32-wide K tiles).
__device__ __forceinline__ int sw_slot(int r, int c) {
  return r * 4 + ((c ^ (r >> 1)) & 3);
}

// proj -> bf16, and mg2[i] = M * ||proj_i||^2 (fp32)
__global__ __launch_bounds__(64) void prep_rf(
    const float* __restrict__ proj, unsigned short* __restrict__ projbf,
    float* __restrict__ mg2) {
  int i = blockIdx.x;
  int lane = threadIdx.x;  // 64 threads
  float4 v = ((const float4*)(proj + (size_t)i * DIMN))[lane];
  ushort4 o;
  o.x = f2bf(v.x); o.y = f2bf(v.y); o.z = f2bf(v.z); o.w = f2bf(v.w);
  ((ushort4*)(projbf + (size_t)i * DIMN))[lane] = o;
  float ss = v.x * v.x + v.y * v.y + v.z * v.z + v.w * v.w;
#pragma unroll
  for (int off = 32; off > 0; off >>= 1) ss += __shfl_down(ss, off, 64);
  if (lane == 0) mg2[i] = MCOEF * ss;
}

// Fused feature kernel for BOTH x (blocks 16..1039) and weights (blocks 0..15).
// K layout is INTERLEAVED: column k = 4*rf + component (identical F and Wp).
__global__ __launch_bounds__(256) void fused_features(
    const float* __restrict__ srcX,          // 65536 x 256 fp32
    const float* __restrict__ srcW,          // 1024 x 256 fp32
    const float* __restrict__ biasW,         // raw b (scaled by 0.25 here)
    const float* __restrict__ xr_g, const float* __restrict__ xi_g,
    const float* __restrict__ mg2_g,
    const unsigned short* __restrict__ projbf,  // 256 x 256 bf16
    unsigned short* __restrict__ FX,         // 65536 x 1024 bf16
    unsigned short* __restrict__ FW,         // 1024 x 1024 bf16
    float sRx, float sRw, float scaleC) {
  __shared__ __align__(16) unsigned short big[16 * 1024];
  unsigned short* As = big;          // 64 rows x 32 k (swizzled slots)
  unsigned short* Bs = big + 2048;   // 256 rows x 32 k (swizzled slots)
  unsigned short* Os = big;          // 16 rows x 1024 cols
  __shared__ float xr_s[256], xi_s[256], c1_s[256], c2_s[256], mg2_s[256];
  __shared__ float sq_s[64], bias_s[64];

  int t = threadIdx.x;
  int lane = t & 63;
  int w = t >> 6;

  bool isW = blockIdx.x < (OUTD / 64);
  int blockRow = isW ? blockIdx.x * 64 : (blockIdx.x - OUTD / 64) * 64;
  const float* src = isW ? srcW : srcX;
  float scl = isW ? 0.25f : (1.f / DIMN);
  unsigned short* Fout = isW ? FW : FX;
  float sR = isW ? sRw : sRx;
  float sI = isW ? -sRw : sRx;

  {
    float a = xr_g[t], b = xi_g[t];
    xr_s[t] = a; xi_s[t] = b;
    c1_s[t] = a * a - b * b;   // Re(z^2)
    c2_s[t] = 2.f * a * b;     // Im(z^2)
    mg2_s[t] = mg2_g[t];
  }
  if (t < 64) bias_s[t] = isW ? biasW[blockRow + t] * 0.25f : 0.f;

  v4f acc[4][4];
#pragma unroll
  for (int a = 0; a < 4; a++)
#pragma unroll
    for (int b = 0; b < 4; b++)
#pragma unroll
      for (int q = 0; q < 4; q++) acc[a][b][q] = 0.f;

  int arow = t >> 2, sub = t & 3;
  const float* srow = src + (size_t)(blockRow + arow) * DIMN + sub * 8;
  float ss = 0.f;

  for (int kb = 0; kb < DIMN; kb += 32) {
    float4 v0 = *(const float4*)(srow + kb);
    float4 v1 = *(const float4*)(srow + kb + 4);
    v0.x *= scl; v0.y *= scl; v0.z *= scl; v0.w *= scl;
    v1.x *= scl; v1.y *= scl; v1.z *= scl; v1.w *= scl;
    ss += v0.x * v0.x + v0.y * v0.y + v0.z * v0.z + v0.w * v0.w +
          v1.x * v1.x + v1.y * v1.y + v1.z * v1.z + v1.w * v1.w;
    us8 o;
    o[0] = f2bf(v0.x); o[1] = f2bf(v0.y); o[2] = f2bf(v0.z); o[3] = f2bf(v0.w);
    o[4] = f2bf(v1.x); o[5] = f2bf(v1.y); o[6] = f2bf(v1.z); o[7] = f2bf(v1.w);
    *(us8*)&As[sw_slot(arow, sub) * 8] = o;
#pragma unroll
    for (int r = 0; r < 4; r++) {
      int idx = r * 256 + t;
      int row = idx >> 2, kc = ((idx & 3) ^ ((idx >> 3) & 3)) * 8;
      async_copy16(projbf + (size_t)row * DIMN + kb + kc,
                   Bs + (idx & ~63) * 8);
    }
    __syncthreads();
    v8bf af[4], bfv[4];
    int c = lane >> 4;
#pragma unroll
    for (int mi = 0; mi < 4; mi++)
      af[mi] = *(const v8bf*)&As[sw_slot(mi * 16 + (lane & 15), c) * 8];
#pragma unroll
    for (int ni = 0; ni < 4; ni++)
      bfv[ni] = *(const v8bf*)&Bs[sw_slot(w * 64 + ni * 16 + (lane & 15), c) * 8];
#pragma unroll
    for (int mi = 0; mi < 4; mi++)
#pragma unroll
      for (int ni = 0; ni < 4; ni++)
        acc[mi][ni] = __builtin_amdgcn_mfma_f32_16x16x32_bf16(
            af[mi], bfv[ni], acc[mi][ni], 0, 0, 0);
    __syncthreads();
  }

  ss += __shfl_xor(ss, 1, 64);
  ss += __shfl_xor(ss, 2, 64);
  if (sub == 0) sq_s[arow] = ss;

#pragma unroll
  for (int mi = 0; mi < 4; mi++) {
    __syncthreads();
#pragma unroll
    for (int ni = 0; ni < 4; ni++) {
      int i = w * 64 + ni * 16 + (lane & 15);  // rf index
      float xrv = xr_s[i], xiv = xi_s[i];
      float c1v = c1_s[i], c2v = c2_s[i], mgv = mg2_s[i];
#pragma unroll
      for (int reg = 0; reg < 4; reg++) {
        int rl    = (lane >> 4) * 4 + reg;
        int rglob = mi * 16 + rl;
        float px = acc[mi][ni][reg];
        float tt = scaleC * px + bias_s[rglob];
        float u  = 0.5f * sq_s[rglob];
        float aa = u * c1v + mgv;
        float bb = u * c2v;
        float txr = tt * xrv;
        float txi = tt * xiv;
        float erp = __expf(txr - aa);
        float erm = __expf(-txr - aa);
        float s1, cc1, s2, cc2;
        __sincosf(txi - bb, &s1, &cc1);
        __sincosf(txi + bb, &s2, &cc2);
        ushort4 ov;
        ov.x = f2bf(sR * erp * cc1);
        ov.y = f2bf(sR * erm * cc2);
        ov.z = f2bf(sI * erp * s1);
        ov.w = f2bf(-sI * erm * s2);
        *(ushort4*)&Os[rl * KDIM + 4 * i] = ov;
      }
    }
    __syncthreads();
#pragma unroll
    for (int j = 0; j < 8; j++) {
      int chunk = j * 256 + t;
      int rowo  = chunk >> 7;
      int off   = (chunk & 127) * 8;
      *(us8*)(Fout + (size_t)(blockRow + mi * 16 + rowo) * KDIM + off) =
          *(const us8*)&Os[rowo * KDIM + off];
    }
  }
}

// ---------------------------------------------------------------------------
// 256x256 8-phase GEMM (T2+T3+T4+T5): out[n,o] = sum_k A[n,k]*B[o,k].
// 512 threads = 8 waves (2M x 4N), per-wave 128x64 output, BK=64, 16 K-tiles.
// LDS 128 KB: double-buffered A(256x64) + B(256x64) bf16 tiles.
// Row permutation: LDS row rho -> global row s.t. each phase's fragments live
// in one contiguous 128-row half (staged as one unit):
//   A: rho = mh*128 + wm*64 + rr   <-> g = wm*128 + mh*64 + rr
//   B: rho = nh*128 + wn*32 + j    <-> g = wn*64  + nh*32 + j
// Swizzle: LDS granule (rho, c) holds global chunk c ^ (rho&7)  (T2, both-sides).
// Staging order/tile: {A-h0, B-h0, B-h1, A-h1}; consumption P1:{Ah0,Bh0},
// P2:{Bh1}, P3:{Ah1}, P4:none. Counted vmcnt(4) at ends of P1,P2,P4 (2 loads
// per half per thread, <=4 halves in flight) -- never 0 in steady state.
// ---------------------------------------------------------------------------
#define WAITV(N) asm volatile("s_waitcnt vmcnt(" #N ")" ::: "memory")

__global__ __launch_bounds__(512) void gemm_bt(
    const unsigned short* __restrict__ A,   // NROWS x KDIM bf16
    const unsigned short* __restrict__ B,   // OUTD x KDIM bf16
    float* __restrict__ C) {                // NROWS x OUTD fp32
  __shared__ __align__(16) unsigned short As[2][256 * 64];
  __shared__ __align__(16) unsigned short Bs[2][256 * 64];
  int tt = threadIdx.x;
  int lane = tt & 63;
  int wv = tt >> 6;
  int wm = wv >> 2, wn = wv & 3;           // 2 x 4 wave grid

  // XCD-aware bijective swizzle (1024 % 8 == 0)
  int lid = blockIdx.x;
  int wg = (lid & 7) * 128 + (lid >> 3);
  size_t bm = (size_t)(wg >> 2) * 256;
  size_t bn = (size_t)(wg & 3) * 256;

  // Per-thread staging source offsets (elements). L = i*512 + tt within a half.
  unsigned int offA[2][2], offB[2][2];
#pragma unroll
  for (int h = 0; h < 2; h++)
#pragma unroll
    for (int i = 0; i < 2; i++) {
      int L = i * 512 + tt;
      int rho = h * 128 + (L >> 3);
      int c = (L & 7) ^ (rho & 7);         // pre-swizzled global chunk
      int gA = ((rho >> 6) & 1) * 128 + (rho >> 7) * 64 + (rho & 63);
      int gB = ((rho >> 5) & 3) * 64 + (rho >> 7) * 32 + (rho & 31);
      offA[h][i] = (unsigned int)((bm + gA) * KDIM + c * 8);
      offB[h][i] = (unsigned int)((bn + gB) * KDIM + c * 8);
    }

#define STAGE_A(H, KB) do { \
  _Pragma("unroll") for (int i_ = 0; i_ < 2; i_++) \
    async_copy16(A + offA[H][i_] + (KB), \
                 &As[nbuf][((H) * 1024 + i_ * 512 + (tt & ~63)) * 8]); \
} while (0)
#define STAGE_B(H, KB) do { \
  _Pragma("unroll") for (int i_ = 0; i_ < 2; i_++) \
    async_copy16(B + offB[H][i_] + (KB), \
                 &Bs[nbuf][((H) * 1024 + i_ * 512 + (tt & ~63)) * 8]); \
} while (0)

  v8bf af[4][2], b0[2][2], b1[2][2];
  v4f acc[8][4];
#pragma unroll
  for (int a = 0; a < 8; a++)
#pragma unroll
    for (int b = 0; b < 4; b++)
#pragma unroll
      for (int q = 0; q < 4; q++) acc[a][b][q] = 0.f;

#define READ_A(MH) do { \
  _Pragma("unroll") for (int mf_ = 0; mf_ < 4; mf_++) { \
    int rho_ = (MH) * 128 + wm * 64 + mf_ * 16 + (lane & 15); \
    int sw_ = rho_ & 7; \
    const unsigned short* rp_ = &As[buf][rho_ * 64]; \
    af[mf_][0] = *(const v8bf*)&rp_[(((lane >> 4)) ^ sw_) * 8]; \
    af[mf_][1] = *(const v8bf*)&rp_[((4 + (lane >> 4)) ^ sw_) * 8]; \
  } \
} while (0)
#define READ_B(NH, DST) do { \
  _Pragma("unroll") for (int nf_ = 0; nf_ < 2; nf_++) { \
    int rho_ = (NH) * 128 + wn * 32 + nf_ * 16 + (lane & 15); \
    int sw_ = rho_ & 7; \
    const unsigned short* rp_ = &Bs[buf][rho_ * 64]; \
    DST[nf_][0] = *(const v8bf*)&rp_[(((lane >> 4)) ^ sw_) * 8]; \
    DST[nf_][1] = *(const v8bf*)&rp_[((4 + (lane >> 4)) ^ sw_) * 8]; \
  } \
} while (0)
#define MMA_Q(MH, NH, BSRC) do { \
  __builtin_amdgcn_s_setprio(1); \
  _Pragma("unroll") for (int mf_ = 0; mf_ < 4; mf_++) \
  _Pragma("unroll") for (int nf_ = 0; nf_ < 2; nf_++) \
  _Pragma("unroll") for (int ks_ = 0; ks_ < 2; ks_++) \
    acc[(MH) * 4 + mf_][(NH) * 2 + nf_] = \
        __builtin_amdgcn_mfma_f32_16x16x32_bf16( \
            af[mf_][ks_], BSRC[nf_][ks_], \
            acc[(MH) * 4 + mf_][(NH) * 2 + nf_], 0, 0, 0); \
  __builtin_amdgcn_s_setprio(0); \
} while (0)

  // Prologue: stage tile 0 fully into buf 0 (order Ah0, Bh0, Bh1, Ah1).
  {
    const int nbuf = 0;
    STAGE_A(0, 0); STAGE_B(0, 0); STAGE_B(1, 0); STAGE_A(1, 0);
  }
  WAITV(4);                         // Ah0 + Bh0 landed (own wave)
  __builtin_amdgcn_s_barrier();     // -> landed for all waves

  for (int t = 0; t < 16; ++t) {
    const int buf = t & 1, nbuf = buf ^ 1;
    const bool pf = (t < 15);
    const int kb = (t + 1) * 64;

    // ---- Phase 1: read Ah0-frags + Bh0-frags, stage Ah0(next), MFMA Q(0,0)
    READ_A(0); READ_B(0, b0);
    if (pf) STAGE_A(0, kb);
    __builtin_amdgcn_s_barrier();
    MMA_Q(0, 0, b0);
    if (pf) { WAITV(4); } else { WAITV(2); }   // next: Bh1 of current tile
    __builtin_amdgcn_s_barrier();

    // ---- Phase 2: read Bh1-frags, stage Bh0(next), MFMA Q(0,1)
    READ_B(1, b1);
    if (pf) STAGE_B(0, kb);
    __builtin_amdgcn_s_barrier();
    MMA_Q(0, 1, b1);
    if (pf) { WAITV(4); } else { WAITV(0); }   // next: Ah1 of current tile
    __builtin_amdgcn_s_barrier();

    // ---- Phase 3: read Ah1-frags, stage Bh1(next), MFMA Q(1,1)
    READ_A(1);
    if (pf) STAGE_B(1, kb);
    __builtin_amdgcn_s_barrier();
    MMA_Q(1, 1, b1);
    __builtin_amdgcn_s_barrier();              // P4 reads nothing: no wait

    // ---- Phase 4: stage Ah1(next), MFMA Q(1,0) (b0 still live)
    if (pf) STAGE_A(1, kb);
    __builtin_amdgcn_s_barrier();
    MMA_Q(1, 0, b0);
    if (pf) { WAITV(4); }                      // next tile P1: Ah0+Bh0 landed
    __builtin_amdgcn_s_barrier();
  }

#pragma unroll
  for (int mf = 0; mf < 8; mf++)
#pragma unroll
    for (int nf = 0; nf < 4; nf++)
#pragma unroll
      for (int reg = 0; reg < 4; reg++) {
        size_t row = bm + wm * 128 + mf * 16 + (lane >> 4) * 4 + reg;
        size_t col = bn + wn * 64 + nf * 16 + (lane & 15);
        C[row * OUTD + col] = acc[mf][nf][reg];
      }
#undef STAGE_A
#undef STAGE_B
#undef READ_A
#undef READ_B
#undef MMA_Q
}

extern "C" void kernel_launch(void* const* d_in, const int* in_sizes, int n_in,
                              void* d_out, int out_size, void* d_ws, size_t ws_size,
                              hipStream_t stream) {
  (void)in_sizes; (void)n_in; (void)out_size;
  const float* x    = (const float*)d_in[0];
  const float* iw   = (const float*)d_in[1];
  const float* bvec = (const float*)d_in[2];
  const float* proj = (const float*)d_in[3];
  const float* xr   = (const float*)d_in[4];
  const float* xi   = (const float*)d_in[5];
  float* out = (float*)d_out;

  char* ws = (char*)d_ws;
  size_t off = 0;
  auto take = [&](size_t bytes) {
    char* p = ws + off;
    off = (off + bytes + 255) & ~(size_t)255;
    return p;
  };
  unsigned short* F      = (unsigned short*)take((size_t)NROWS * KDIM * 2);  // 134 MB
  unsigned short* Wp     = (unsigned short*)take((size_t)OUTD * KDIM * 2);   // 2 MB
  unsigned short* projbf = (unsigned short*)take((size_t)NRF * DIMN * 2);    // 128 KB
  float* mg2 = (float*)take((size_t)NRF * 4);
  if (ws_size < off) return;

  const float  scaleC = sqrtf(1.f + 4.f * MCOEF);
  const double c2d    = 0.5 * exp(128.0 * log(1.0 + 4.0 * 0.001));
  const float  invSR  = 0.0625f;
  const float  sRw    = (float)(c2d * 0.0625);

  prep_rf<<<NRF, 64, 0, stream>>>(proj, projbf, mg2);
  fused_features<<<NROWS / 64 + OUTD / 64, 256, 0, stream>>>(
      x, iw, bvec, xr, xi, mg2, projbf, F, Wp, invSR, sRw, scaleC);
  gemm_bt<<<1024, 512, 0, stream>>>(F, Wp, out);
}

// Round 3
// 496.950 us; speedup vs baseline: 1.1417x; 1.0199x over previous
//
#include <hip/hip_runtime.h>
#include <cmath>
#include <cstdint>

#define NROWS 65536
#define DIMN  256
#define NRF   256
#define OUTD  1024
#define KDIM  1024   // 4*NRF
#define MCOEF 0.001f

typedef __bf16 v8bf __attribute__((ext_vector_type(8)));
typedef float  v4f  __attribute__((ext_vector_type(4)));
typedef unsigned short us8 __attribute__((ext_vector_type(8)));

__device__ __forceinline__ unsigned short f2bf(float f) {
  unsigned int u = __float_as_uint(f);
  u += 0x7fffu + ((u >> 16) & 1u);   // round-to-nearest-even
  return (unsigned short)(u >> 16);
}

__device__ __forceinline__ void async_copy16(const void* g, void* l) {
  __builtin_amdgcn_global_load_lds(
      (const __attribute__((address_space(1))) void*)g,
      (__attribute__((address_space(3))) void*)l, 16, 0, 0);
}

// XOR-swizzled tile layout for the feature kernel (32-wide K tiles).
__device__ __forceinline__ int sw_slot(int r, int c) {
  return r * 4 + ((c ^ (r >> 1)) & 3);
}

// proj -> bf16, and mg2[i] = M * ||proj_i||^2 (fp32)
__global__ __launch_bounds__(64) void prep_rf(
    const float* __restrict__ proj, unsigned short* __restrict__ projbf,
    float* __restrict__ mg2) {
  int i = blockIdx.x;
  int lane = threadIdx.x;  // 64 threads
  float4 v = ((const float4*)(proj + (size_t)i * DIMN))[lane];
  ushort4 o;
  o.x = f2bf(v.x); o.y = f2bf(v.y); o.z = f2bf(v.z); o.w = f2bf(v.w);
  ((ushort4*)(projbf + (size_t)i * DIMN))[lane] = o;
  float ss = v.x * v.x + v.y * v.y + v.z * v.z + v.w * v.w;
#pragma unroll
  for (int off = 32; off > 0; off >>= 1) ss += __shfl_down(ss, off, 64);
  if (lane == 0) mg2[i] = MCOEF * ss;
}

// Fused feature kernel for BOTH x (blocks 16..1039) and weights (blocks 0..15).
// K layout INTERLEAVED: column k = 4*rf + component (identical F and Wp).
// v3: 2-phase prefetch K-loop (double-buffered As/Bs, stage k+1 before
// computing k, ONE barrier/iter) + direct ushort4 epilogue stores (no Os
// LDS round-trip, no epilogue barriers). Barriers/block: 24 -> 10.
__global__ __launch_bounds__(256) void fused_features(
    const float* __restrict__ srcX,          // 65536 x 256 fp32
    const float* __restrict__ srcW,          // 1024 x 256 fp32
    const float* __restrict__ biasW,         // raw b (scaled by 0.25 here)
    const float* __restrict__ xr_g, const float* __restrict__ xi_g,
    const float* __restrict__ mg2_g,
    const unsigned short* __restrict__ projbf,  // 256 x 256 bf16
    unsigned short* __restrict__ FX,         // 65536 x 1024 bf16
    unsigned short* __restrict__ FW,         // 1024 x 1024 bf16
    float sRx, float sRw, float scaleC) {
  __shared__ __align__(16) unsigned short As[2][64 * 32];    // 2 x 4 KB
  __shared__ __align__(16) unsigned short Bs[2][256 * 32];   // 2 x 16 KB
  __shared__ float xr_s[256], xi_s[256], c1_s[256], c2_s[256], mg2_s[256];
  __shared__ float sq_s[64], bias_s[64];

  int t = threadIdx.x;
  int lane = t & 63;
  int w = t >> 6;

  bool isW = blockIdx.x < (OUTD / 64);
  int blockRow = isW ? blockIdx.x * 64 : (blockIdx.x - OUTD / 64) * 64;
  const float* src = isW ? srcW : srcX;
  float scl = isW ? 0.25f : (1.f / DIMN);
  unsigned short* Fout = isW ? FW : FX;
  float sR = isW ? sRw : sRx;
  float sI = isW ? -sRw : sRx;

  {
    float a = xr_g[t], b = xi_g[t];
    xr_s[t] = a; xi_s[t] = b;
    c1_s[t] = a * a - b * b;   // Re(z^2)
    c2_s[t] = 2.f * a * b;     // Im(z^2)
    mg2_s[t] = mg2_g[t];
  }
  if (t < 64) bias_s[t] = isW ? biasW[blockRow + t] * 0.25f : 0.f;

  v4f acc[4][4];
#pragma unroll
  for (int a = 0; a < 4; a++)
#pragma unroll
    for (int b = 0; b < 4; b++)
#pragma unroll
      for (int q = 0; q < 4; q++) acc[a][b][q] = 0.f;

  int arow = t >> 2, sub = t & 3;
  const float* srow = src + (size_t)(blockRow + arow) * DIMN + sub * 8;
  float ss = 0.f;

  // B: 256x32 tile = 16 KB via global_load_lds, source-chunk swizzled
  auto stageB = [&](int nb, int kb) {
#pragma unroll
    for (int r = 0; r < 4; r++) {
      int idx = r * 256 + t;
      int row = idx >> 2, kc = ((idx & 3) ^ ((idx >> 3) & 3)) * 8;
      async_copy16(projbf + (size_t)row * DIMN + kb + kc,
                   &Bs[nb][(idx & ~63) * 8]);
    }
  };
  // A: fp32 load -> scale -> bf16 -> LDS swizzled slot (+ sum of squares)
  auto stageA = [&](int nb, int kb) {
    float4 v0 = *(const float4*)(srow + kb);
    float4 v1 = *(const float4*)(srow + kb + 4);
    v0.x *= scl; v0.y *= scl; v0.z *= scl; v0.w *= scl;
    v1.x *= scl; v1.y *= scl; v1.z *= scl; v1.w *= scl;
    ss += v0.x * v0.x + v0.y * v0.y + v0.z * v0.z + v0.w * v0.w +
          v1.x * v1.x + v1.y * v1.y + v1.z * v1.z + v1.w * v1.w;
    us8 o;
    o[0] = f2bf(v0.x); o[1] = f2bf(v0.y); o[2] = f2bf(v0.z); o[3] = f2bf(v0.w);
    o[4] = f2bf(v1.x); o[5] = f2bf(v1.y); o[6] = f2bf(v1.z); o[7] = f2bf(v1.w);
    *(us8*)&As[nb][sw_slot(arow, sub) * 8] = o;
  };

  // Prologue: tile 0 into buf 0. (__syncthreads drains the copies.)
  stageB(0, 0);
  stageA(0, 0);
  __syncthreads();

  for (int kb = 0; kb < 8; kb++) {
    int cur = kb & 1, nb = cur ^ 1;
    if (kb < 7) {              // prefetch k+1: in flight under reads+MFMA
      stageB(nb, (kb + 1) * 32);
      stageA(nb, (kb + 1) * 32);
    }
    v8bf af[4], bfv[4];
    int c = lane >> 4;
#pragma unroll
    for (int mi = 0; mi < 4; mi++)
      af[mi] = *(const v8bf*)&As[cur][sw_slot(mi * 16 + (lane & 15), c) * 8];
#pragma unroll
    for (int ni = 0; ni < 4; ni++)
      bfv[ni] = *(const v8bf*)&Bs[cur][sw_slot(w * 64 + ni * 16 + (lane & 15), c) * 8];
#pragma unroll
    for (int mi = 0; mi < 4; mi++)
#pragma unroll
      for (int ni = 0; ni < 4; ni++)
        acc[mi][ni] = __builtin_amdgcn_mfma_f32_16x16x32_bf16(
            af[mi], bfv[ni], acc[mi][ni], 0, 0, 0);
    __syncthreads();           // nb staged for all; everyone done reading cur
  }

  // row sum-of-squares: reduce the 4 sub-threads of each row
  ss += __shfl_xor(ss, 1, 64);
  ss += __shfl_xor(ss, 2, 64);
  if (sub == 0) sq_s[arow] = ss;
  __syncthreads();

  // Epilogue: compute features, store ushort4 direct to global.
  // For fixed (mi,ni,reg): 16 lanes write 128 contiguous bytes.
#pragma unroll
  for (int mi = 0; mi < 4; mi++)
#pragma unroll
    for (int ni = 0; ni < 4; ni++) {
      int i = w * 64 + ni * 16 + (lane & 15);  // rf index
      float xrv = xr_s[i], xiv = xi_s[i];
      float c1v = c1_s[i], c2v = c2_s[i], mgv = mg2_s[i];
#pragma unroll
      for (int reg = 0; reg < 4; reg++) {
        int rglob = mi * 16 + (lane >> 4) * 4 + reg;   // row within block
        float px = acc[mi][ni][reg];
        float tt = scaleC * px + bias_s[rglob];
        float u  = 0.5f * sq_s[rglob];
        float aa = u * c1v + mgv;
        float bb = u * c2v;
        float txr = tt * xrv;
        float txi = tt * xiv;
        float erp = __expf(txr - aa);
        float erm = __expf(-txr - aa);
        float s1, cc1, s2, cc2;
        __sincosf(txi - bb, &s1, &cc1);
        __sincosf(txi + bb, &s2, &cc2);
        ushort4 ov;
        ov.x = f2bf(sR * erp * cc1);
        ov.y = f2bf(sR * erm * cc2);
        ov.z = f2bf(sI * erp * s1);
        ov.w = f2bf(-sI * erm * s2);
        *(ushort4*)(Fout + (size_t)(blockRow + rglob) * KDIM + 4 * i) = ov;
      }
    }
}

// ---------------------------------------------------------------------------
// 256x256 8-phase GEMM (T2+T3+T4+T5): out[n,o] = sum_k A[n,k]*B[o,k].
// 512 threads = 8 waves (2M x 4N), per-wave 128x64 output, BK=64, 16 K-tiles.
// LDS 128 KB: double-buffered A(256x64) + B(256x64) bf16 tiles.
// Row permutation: LDS row rho -> global row s.t. each phase's fragments live
// in one contiguous 128-row half (staged as one unit):
//   A: rho = mh*128 + wm*64 + rr   <-> g = wm*128 + mh*64 + rr
//   B: rho = nh*128 + wn*32 + j    <-> g = wn*64  + nh*32 + j
// Swizzle: LDS granule (rho, c) holds global chunk c ^ (rho&7)  (T2, both-sides).
// Staging order/tile: {A-h0, B-h0, B-h1, A-h1}; consumption P1:{Ah0,Bh0},
// P2:{Bh1}, P3:{Ah1}, P4:none. Counted vmcnt(4) at ends of P1,P2,P4 (2 loads
// per half per thread, <=4 halves in flight) -- never 0 in steady state.
// ---------------------------------------------------------------------------
#define WAITV(N) asm volatile("s_waitcnt vmcnt(" #N ")" ::: "memory")

__global__ __launch_bounds__(512) void gemm_bt(
    const unsigned short* __restrict__ A,   // NROWS x KDIM bf16
    const unsigned short* __restrict__ B,   // OUTD x KDIM bf16
    float* __restrict__ C) {                // NROWS x OUTD fp32
  __shared__ __align__(16) unsigned short As[2][256 * 64];
  __shared__ __align__(16) unsigned short Bs[2][256 * 64];
  int tt = threadIdx.x;
  int lane = tt & 63;
  int wv = tt >> 6;
  int wm = wv >> 2, wn = wv & 3;           // 2 x 4 wave grid

  // XCD-aware bijective swizzle (1024 % 8 == 0)
  int lid = blockIdx.x;
  int wg = (lid & 7) * 128 + (lid >> 3);
  size_t bm = (size_t)(wg >> 2) * 256;
  size_t bn = (size_t)(wg & 3) * 256;

  // Per-thread staging source offsets (elements). L = i*512 + tt within a half.
  unsigned int offA[2][2], offB[2][2];
#pragma unroll
  for (int h = 0; h < 2; h++)
#pragma unroll
    for (int i = 0; i < 2; i++) {
      int L = i * 512 + tt;
      int rho = h * 128 + (L >> 3);
      int c = (L & 7) ^ (rho & 7);         // pre-swizzled global chunk
      int gA = ((rho >> 6) & 1) * 128 + (rho >> 7) * 64 + (rho & 63);
      int gB = ((rho >> 5) & 3) * 64 + (rho >> 7) * 32 + (rho & 31);
      offA[h][i] = (unsigned int)((bm + gA) * KDIM + c * 8);
      offB[h][i] = (unsigned int)((bn + gB) * KDIM + c * 8);
    }

#define STAGE_A(H, KB) do { \
  _Pragma("unroll") for (int i_ = 0; i_ < 2; i_++) \
    async_copy16(A + offA[H][i_] + (KB), \
                 &As[nbuf][((H) * 1024 + i_ * 512 + (tt & ~63)) * 8]); \
} while (0)
#define STAGE_B(H, KB) do { \
  _Pragma("unroll") for (int i_ = 0; i_ < 2; i_++) \
    async_copy16(B + offB[H][i_] + (KB), \
                 &Bs[nbuf][((H) * 1024 + i_ * 512 + (tt & ~63)) * 8]); \
} while (0)

  v8bf af[4][2], b0[2][2], b1[2][2];
  v4f acc[8][4];
#pragma unroll
  for (int a = 0; a < 8; a++)
#pragma unroll
    for (int b = 0; b < 4; b++)
#pragma unroll
      for (int q = 0; q < 4; q++) acc[a][b][q] = 0.f;

#define READ_A(MH) do { \
  _Pragma("unroll") for (int mf_ = 0; mf_ < 4; mf_++) { \
    int rho_ = (MH) * 128 + wm * 64 + mf_ * 16 + (lane & 15); \
    int sw_ = rho_ & 7; \
    const unsigned short* rp_ = &As[buf][rho_ * 64]; \
    af[mf_][0] = *(const v8bf*)&rp_[(((lane >> 4)) ^ sw_) * 8]; \
    af[mf_][1] = *(const v8bf*)&rp_[((4 + (lane >> 4)) ^ sw_) * 8]; \
  } \
} while (0)
#define READ_B(NH, DST) do { \
  _Pragma("unroll") for (int nf_ = 0; nf_ < 2; nf_++) { \
    int rho_ = (NH) * 128 + wn * 32 + nf_ * 16 + (lane & 15); \
    int sw_ = rho_ & 7; \
    const unsigned short* rp_ = &Bs[buf][rho_ * 64]; \
    DST[nf_][0] = *(const v8bf*)&rp_[(((lane >> 4)) ^ sw_) * 8]; \
    DST[nf_][1] = *(const v8bf*)&rp_[((4 + (lane >> 4)) ^ sw_) * 8]; \
  } \
} while (0)
#define MMA_Q(MH, NH, BSRC) do { \
  __builtin_amdgcn_s_setprio(1); \
  _Pragma("unroll") for (int mf_ = 0; mf_ < 4; mf_++) \
  _Pragma("unroll") for (int nf_ = 0; nf_ < 2; nf_++) \
  _Pragma("unroll") for (int ks_ = 0; ks_ < 2; ks_++) \
    acc[(MH) * 4 + mf_][(NH) * 2 + nf_] = \
        __builtin_amdgcn_mfma_f32_16x16x32_bf16( \
            af[mf_][ks_], BSRC[nf_][ks_], \
            acc[(MH) * 4 + mf_][(NH) * 2 + nf_], 0, 0, 0); \
  __builtin_amdgcn_s_setprio(0); \
} while (0)

  // Prologue: stage tile 0 fully into buf 0 (order Ah0, Bh0, Bh1, Ah1).
  {
    const int nbuf = 0;
    STAGE_A(0, 0); STAGE_B(0, 0); STAGE_B(1, 0); STAGE_A(1, 0);
  }
  WAITV(4);                         // Ah0 + Bh0 landed (own wave)
  __builtin_amdgcn_s_barrier();     // -> landed for all waves

  for (int t = 0; t < 16; ++t) {
    const int buf = t & 1, nbuf = buf ^ 1;
    const bool pf = (t < 15);
    const int kb = (t + 1) * 64;

    // ---- Phase 1: read Ah0-frags + Bh0-frags, stage Ah0(next), MFMA Q(0,0)
    READ_A(0); READ_B(0, b0);
    if (pf) STAGE_A(0, kb);
    __builtin_amdgcn_s_barrier();
    MMA_Q(0, 0, b0);
    if (pf) { WAITV(4); } else { WAITV(2); }   // next: Bh1 of current tile
    __builtin_amdgcn_s_barrier();

    // ---- Phase 2: read Bh1-frags, stage Bh0(next), MFMA Q(0,1)
    READ_B(1, b1);
    if (pf) STAGE_B(0, kb);
    __builtin_amdgcn_s_barrier();
    MMA_Q(0, 1, b1);
    if (pf) { WAITV(4); } else { WAITV(0); }   // next: Ah1 of current tile
    __builtin_amdgcn_s_barrier();

    // ---- Phase 3: read Ah1-frags, stage Bh1(next), MFMA Q(1,1)
    READ_A(1);
    if (pf) STAGE_B(1, kb);
    __builtin_amdgcn_s_barrier();
    MMA_Q(1, 1, b1);
    __builtin_amdgcn_s_barrier();              // P4 reads nothing: no wait

    // ---- Phase 4: stage Ah1(next), MFMA Q(1,0) (b0 still live)
    if (pf) STAGE_A(1, kb);
    __builtin_amdgcn_s_barrier();
    MMA_Q(1, 0, b0);
    if (pf) { WAITV(4); }                      // next tile P1: Ah0+Bh0 landed
    __builtin_amdgcn_s_barrier();
  }

#pragma unroll
  for (int mf = 0; mf < 8; mf++)
#pragma unroll
    for (int nf = 0; nf < 4; nf++)
#pragma unroll
      for (int reg = 0; reg < 4; reg++) {
        size_t row = bm + wm * 128 + mf * 16 + (lane >> 4) * 4 + reg;
        size_t col = bn + wn * 64 + nf * 16 + (lane & 15);
        C[row * OUTD + col] = acc[mf][nf][reg];
      }
#undef STAGE_A
#undef STAGE_B
#undef READ_A
#undef READ_B
#undef MMA_Q
}

extern "C" void kernel_launch(void* const* d_in, const int* in_sizes, int n_in,
                              void* d_out, int out_size, void* d_ws, size_t ws_size,
                              hipStream_t stream) {
  (void)in_sizes; (void)n_in; (void)out_size;
  const float* x    = (const float*)d_in[0];
  const float* iw   = (const float*)d_in[1];
  const float* bvec = (const float*)d_in[2];
  const float* proj = (const float*)d_in[3];
  const float* xr   = (const float*)d_in[4];
  const float* xi   = (const float*)d_in[5];
  float* out = (float*)d_out;

  char* ws = (char*)d_ws;
  size_t off = 0;
  auto take = [&](size_t bytes) {
    char* p = ws + off;
    off = (off + bytes + 255) & ~(size_t)255;
    return p;
  };
  unsigned short* F      = (unsigned short*)take((size_t)NROWS * KDIM * 2);  // 134 MB
  unsigned short* Wp     = (unsigned short*)take((size_t)OUTD * KDIM * 2);   // 2 MB
  unsigned short* projbf = (unsigned short*)take((size_t)NRF * DIMN * 2);    // 128 KB
  float* mg2 = (float*)take((size_t)NRF * 4);
  if (ws_size < off) return;

  const float  scaleC = sqrtf(1.f + 4.f * MCOEF);
  const double c2d    = 0.5 * exp(128.0 * log(1.0 + 4.0 * 0.001));
  const float  invSR  = 0.0625f;
  const float  sRw    = (float)(c2d * 0.0625);

  prep_rf<<<NRF, 64, 0, stream>>>(proj, projbf, mg2);
  fused_features<<<NROWS / 64 + OUTD / 64, 256, 0, stream>>>(
      x, iw, bvec, xr, xi, mg2, projbf, F, Wp, invSR, sRw, scaleC);
  gemm_bt<<<1024, 512, 0, stream>>>(F, Wp, out);
}

// Round 4
// 491.831 us; speedup vs baseline: 1.1536x; 1.0104x over previous
//
#include <hip/hip_runtime.h>
#include <cmath>
#include <cstdint>

#define NROWS 65536
#define DIMN  256
#define NRF   256
#define OUTD  1024
#define KDIM  1024   // 4*NRF
#define MCOEF 0.001f

typedef __bf16 v8bf __attribute__((ext_vector_type(8)));
typedef float  v4f  __attribute__((ext_vector_type(4)));
typedef float  f32x16 __attribute__((ext_vector_type(16)));
typedef unsigned short us8 __attribute__((ext_vector_type(8)));

__device__ __forceinline__ unsigned short f2bf(float f) {
  unsigned int u = __float_as_uint(f);
  u += 0x7fffu + ((u >> 16) & 1u);   // round-to-nearest-even
  return (unsigned short)(u >> 16);
}

__device__ __forceinline__ void async_copy16(const void* g, void* l) {
  __builtin_amdgcn_global_load_lds(
      (const __attribute__((address_space(1))) void*)g,
      (__attribute__((address_space(3))) void*)l, 16, 0, 0);
}

// XOR-swizzled tile layout for the feature kernel (32-wide K tiles).
__device__ __forceinline__ int sw_slot(int r, int c) {
  return r * 4 + ((c ^ (r >> 1)) & 3);
}

// proj -> bf16, and mg2[i] = M * ||proj_i||^2 (fp32)
__global__ __launch_bounds__(64) void prep_rf(
    const float* __restrict__ proj, unsigned short* __restrict__ projbf,
    float* __restrict__ mg2) {
  int i = blockIdx.x;
  int lane = threadIdx.x;  // 64 threads
  float4 v = ((const float4*)(proj + (size_t)i * DIMN))[lane];
  ushort4 o;
  o.x = f2bf(v.x); o.y = f2bf(v.y); o.z = f2bf(v.z); o.w = f2bf(v.w);
  ((ushort4*)(projbf + (size_t)i * DIMN))[lane] = o;
  float ss = v.x * v.x + v.y * v.y + v.z * v.z + v.w * v.w;
#pragma unroll
  for (int off = 32; off > 0; off >>= 1) ss += __shfl_down(ss, off, 64);
  if (lane == 0) mg2[i] = MCOEF * ss;
}

// Fused feature kernel for BOTH x (blocks 16..1039) and weights (blocks 0..15).
// K layout INTERLEAVED: column k = 4*rf + component (identical F and Wp).
// 2-phase prefetch K-loop + direct ushort4 epilogue stores.
__global__ __launch_bounds__(256) void fused_features(
    const float* __restrict__ srcX,          // 65536 x 256 fp32
    const float* __restrict__ srcW,          // 1024 x 256 fp32
    const float* __restrict__ biasW,         // raw b (scaled by 0.25 here)
    const float* __restrict__ xr_g, const float* __restrict__ xi_g,
    const float* __restrict__ mg2_g,
    const unsigned short* __restrict__ projbf,  // 256 x 256 bf16
    unsigned short* __restrict__ FX,         // 65536 x 1024 bf16
    unsigned short* __restrict__ FW,         // 1024 x 1024 bf16
    float sRx, float sRw, float scaleC) {
  __shared__ __align__(16) unsigned short As[2][64 * 32];    // 2 x 4 KB
  __shared__ __align__(16) unsigned short Bs[2][256 * 32];   // 2 x 16 KB
  __shared__ float xr_s[256], xi_s[256], c1_s[256], c2_s[256], mg2_s[256];
  __shared__ float sq_s[64], bias_s[64];

  int t = threadIdx.x;
  int lane = t & 63;
  int w = t >> 6;

  bool isW = blockIdx.x < (OUTD / 64);
  int blockRow = isW ? blockIdx.x * 64 : (blockIdx.x - OUTD / 64) * 64;
  const float* src = isW ? srcW : srcX;
  float scl = isW ? 0.25f : (1.f / DIMN);
  unsigned short* Fout = isW ? FW : FX;
  float sR = isW ? sRw : sRx;
  float sI = isW ? -sRw : sRx;

  {
    float a = xr_g[t], b = xi_g[t];
    xr_s[t] = a; xi_s[t] = b;
    c1_s[t] = a * a - b * b;   // Re(z^2)
    c2_s[t] = 2.f * a * b;     // Im(z^2)
    mg2_s[t] = mg2_g[t];
  }
  if (t < 64) bias_s[t] = isW ? biasW[blockRow + t] * 0.25f : 0.f;

  v4f acc[4][4];
#pragma unroll
  for (int a = 0; a < 4; a++)
#pragma unroll
    for (int b = 0; b < 4; b++)
#pragma unroll
      for (int q = 0; q < 4; q++) acc[a][b][q] = 0.f;

  int arow = t >> 2, sub = t & 3;
  const float* srow = src + (size_t)(blockRow + arow) * DIMN + sub * 8;
  float ss = 0.f;

  auto stageB = [&](int nb, int kb) {
#pragma unroll
    for (int r = 0; r < 4; r++) {
      int idx = r * 256 + t;
      int row = idx >> 2, kc = ((idx & 3) ^ ((idx >> 3) & 3)) * 8;
      async_copy16(projbf + (size_t)row * DIMN + kb + kc,
                   &Bs[nb][(idx & ~63) * 8]);
    }
  };
  auto stageA = [&](int nb, int kb) {
    float4 v0 = *(const float4*)(srow + kb);
    float4 v1 = *(const float4*)(srow + kb + 4);
    v0.x *= scl; v0.y *= scl; v0.z *= scl; v0.w *= scl;
    v1.x *= scl; v1.y *= scl; v1.z *= scl; v1.w *= scl;
    ss += v0.x * v0.x + v0.y * v0.y + v0.z * v0.z + v0.w * v0.w +
          v1.x * v1.x + v1.y * v1.y + v1.z * v1.z + v1.w * v1.w;
    us8 o;
    o[0] = f2bf(v0.x); o[1] = f2bf(v0.y); o[2] = f2bf(v0.z); o[3] = f2bf(v0.w);
    o[4] = f2bf(v1.x); o[5] = f2bf(v1.y); o[6] = f2bf(v1.z); o[7] = f2bf(v1.w);
    *(us8*)&As[nb][sw_slot(arow, sub) * 8] = o;
  };

  stageB(0, 0);
  stageA(0, 0);
  __syncthreads();

  for (int kb = 0; kb < 8; kb++) {
    int cur = kb & 1, nb = cur ^ 1;
    if (kb < 7) {
      stageB(nb, (kb + 1) * 32);
      stageA(nb, (kb + 1) * 32);
    }
    v8bf af[4], bfv[4];
    int c = lane >> 4;
#pragma unroll
    for (int mi = 0; mi < 4; mi++)
      af[mi] = *(const v8bf*)&As[cur][sw_slot(mi * 16 + (lane & 15), c) * 8];
#pragma unroll
    for (int ni = 0; ni < 4; ni++)
      bfv[ni] = *(const v8bf*)&Bs[cur][sw_slot(w * 64 + ni * 16 + (lane & 15), c) * 8];
#pragma unroll
    for (int mi = 0; mi < 4; mi++)
#pragma unroll
      for (int ni = 0; ni < 4; ni++)
        acc[mi][ni] = __builtin_amdgcn_mfma_f32_16x16x32_bf16(
            af[mi], bfv[ni], acc[mi][ni], 0, 0, 0);
    __syncthreads();
  }

  ss += __shfl_xor(ss, 1, 64);
  ss += __shfl_xor(ss, 2, 64);
  if (sub == 0) sq_s[arow] = ss;
  __syncthreads();

#pragma unroll
  for (int mi = 0; mi < 4; mi++)
#pragma unroll
    for (int ni = 0; ni < 4; ni++) {
      int i = w * 64 + ni * 16 + (lane & 15);  // rf index
      float xrv = xr_s[i], xiv = xi_s[i];
      float c1v = c1_s[i], c2v = c2_s[i], mgv = mg2_s[i];
#pragma unroll
      for (int reg = 0; reg < 4; reg++) {
        int rglob = mi * 16 + (lane >> 4) * 4 + reg;   // row within block
        float px = acc[mi][ni][reg];
        float tt = scaleC * px + bias_s[rglob];
        float u  = 0.5f * sq_s[rglob];
        float aa = u * c1v + mgv;
        float bb = u * c2v;
        float txr = tt * xrv;
        float txi = tt * xiv;
        float erp = __expf(txr - aa);
        float erm = __expf(-txr - aa);
        float s1, cc1, s2, cc2;
        __sincosf(txi - bb, &s1, &cc1);
        __sincosf(txi + bb, &s2, &cc2);
        ushort4 ov;
        ov.x = f2bf(sR * erp * cc1);
        ov.y = f2bf(sR * erm * cc2);
        ov.z = f2bf(sI * erp * s1);
        ov.w = f2bf(-sI * erm * s2);
        *(ushort4*)(Fout + (size_t)(blockRow + rglob) * KDIM + 4 * i) = ov;
      }
    }
}

// ---------------------------------------------------------------------------
// 256x256 8-phase GEMM, now on mfma_f32_32x32x16_bf16 (higher ceiling, half
// the MFMA instructions). Staging skeleton (row permutation, swizzle, vmcnt
// schedule, barriers) is UNCHANGED from the verified 16x16 version — only
// fragment reads, accumulator shape, and C-write changed.
//   A-frag (32x32x16): row = lane&31, k = (lane>>5)*8 + e (contiguous 8)
//   C/D: col = lane&31, row = (reg&3) + 8*(reg>>2) + 4*(lane>>5), reg in [0,16)
// Per wave: 128x64 output = 4 row-frags x 2 col-frags of 32x32, acc 128 VGPR.
// Per phase: read one row/col half + 8 MFMA; per tile BK=64 = 4 ks of 16.
// ---------------------------------------------------------------------------
#define WAITV(N) asm volatile("s_waitcnt vmcnt(" #N ")" ::: "memory")

__global__ __launch_bounds__(512) void gemm_bt(
    const unsigned short* __restrict__ A,   // NROWS x KDIM bf16
    const unsigned short* __restrict__ B,   // OUTD x KDIM bf16
    float* __restrict__ C) {                // NROWS x OUTD fp32
  __shared__ __align__(16) unsigned short As[2][256 * 64];
  __shared__ __align__(16) unsigned short Bs[2][256 * 64];
  int tt = threadIdx.x;
  int lane = tt & 63;
  int wv = tt >> 6;
  int wm = wv >> 2, wn = wv & 3;           // 2 x 4 wave grid

  // XCD-aware bijective swizzle (1024 % 8 == 0)
  int lid = blockIdx.x;
  int wg = (lid & 7) * 128 + (lid >> 3);
  size_t bm = (size_t)(wg >> 2) * 256;
  size_t bn = (size_t)(wg & 3) * 256;

  // Per-thread staging source offsets (elements). L = i*512 + tt within a half.
  unsigned int offA[2][2], offB[2][2];
#pragma unroll
  for (int h = 0; h < 2; h++)
#pragma unroll
    for (int i = 0; i < 2; i++) {
      int L = i * 512 + tt;
      int rho = h * 128 + (L >> 3);
      int c = (L & 7) ^ (rho & 7);         // pre-swizzled global chunk
      int gA = ((rho >> 6) & 1) * 128 + (rho >> 7) * 64 + (rho & 63);
      int gB = ((rho >> 5) & 3) * 64 + (rho >> 7) * 32 + (rho & 31);
      offA[h][i] = (unsigned int)((bm + gA) * KDIM + c * 8);
      offB[h][i] = (unsigned int)((bn + gB) * KDIM + c * 8);
    }

#define STAGE_A(H, KB) do { \
  _Pragma("unroll") for (int i_ = 0; i_ < 2; i_++) \
    async_copy16(A + offA[H][i_] + (KB), \
                 &As[nbuf][((H) * 1024 + i_ * 512 + (tt & ~63)) * 8]); \
} while (0)
#define STAGE_B(H, KB) do { \
  _Pragma("unroll") for (int i_ = 0; i_ < 2; i_++) \
    async_copy16(B + offB[H][i_] + (KB), \
                 &Bs[nbuf][((H) * 1024 + i_ * 512 + (tt & ~63)) * 8]); \
} while (0)

  // af[mf_][ks]: A frags for current row-half (mf_ 0..1), ks 0..3
  v8bf af[2][4], b0[4], b1[4];
  f32x16 acc[4][2];
#pragma unroll
  for (int a = 0; a < 4; a++)
#pragma unroll
    for (int b = 0; b < 2; b++)
#pragma unroll
      for (int q = 0; q < 16; q++) acc[a][b][q] = 0.f;

#define READ_A(MH) do { \
  _Pragma("unroll") for (int mf_ = 0; mf_ < 2; mf_++) { \
    int rho_ = (MH) * 128 + wm * 64 + mf_ * 32 + (lane & 31); \
    int sw_ = rho_ & 7; \
    const unsigned short* rp_ = &As[buf][rho_ * 64]; \
    _Pragma("unroll") for (int ks_ = 0; ks_ < 4; ks_++) \
      af[mf_][ks_] = *(const v8bf*)&rp_[((2 * ks_ + (lane >> 5)) ^ sw_) * 8]; \
  } \
} while (0)
#define READ_B(NH, DST) do { \
  { \
    int rho_ = (NH) * 128 + wn * 32 + (lane & 31); \
    int sw_ = rho_ & 7; \
    const unsigned short* rp_ = &Bs[buf][rho_ * 64]; \
    _Pragma("unroll") for (int ks_ = 0; ks_ < 4; ks_++) \
      DST[ks_] = *(const v8bf*)&rp_[((2 * ks_ + (lane >> 5)) ^ sw_) * 8]; \
  } \
} while (0)
#define MMA_Q(MH, NH, BSRC) do { \
  __builtin_amdgcn_s_setprio(1); \
  _Pragma("unroll") for (int mf_ = 0; mf_ < 2; mf_++) \
  _Pragma("unroll") for (int ks_ = 0; ks_ < 4; ks_++) \
    acc[(MH) * 2 + mf_][NH] = __builtin_amdgcn_mfma_f32_32x32x16_bf16( \
        af[mf_][ks_], BSRC[ks_], acc[(MH) * 2 + mf_][NH], 0, 0, 0); \
  __builtin_amdgcn_s_setprio(0); \
} while (0)

  // Prologue: stage tile 0 fully into buf 0 (order Ah0, Bh0, Bh1, Ah1).
  {
    const int nbuf = 0;
    STAGE_A(0, 0); STAGE_B(0, 0); STAGE_B(1, 0); STAGE_A(1, 0);
  }
  WAITV(4);                         // Ah0 + Bh0 landed (own wave)
  __builtin_amdgcn_s_barrier();     // -> landed for all waves

  for (int t = 0; t < 16; ++t) {
    const int buf = t & 1, nbuf = buf ^ 1;
    const bool pf = (t < 15);
    const int kb = (t + 1) * 64;

    // ---- Phase 1: read Ah0 + Bh0 frags, stage Ah0(next), MFMA Q(0,0)
    READ_A(0); READ_B(0, b0);
    if (pf) STAGE_A(0, kb);
    __builtin_amdgcn_s_barrier();
    MMA_Q(0, 0, b0);
    if (pf) { WAITV(4); } else { WAITV(2); }   // next: Bh1 of current tile
    __builtin_amdgcn_s_barrier();

    // ---- Phase 2: read Bh1 frags, stage Bh0(next), MFMA Q(0,1)
    READ_B(1, b1);
    if (pf) STAGE_B(0, kb);
    __builtin_amdgcn_s_barrier();
    MMA_Q(0, 1, b1);
    if (pf) { WAITV(4); } else { WAITV(0); }   // next: Ah1 of current tile
    __builtin_amdgcn_s_barrier();

    // ---- Phase 3: read Ah1 frags, stage Bh1(next), MFMA Q(1,1)
    READ_A(1);
    if (pf) STAGE_B(1, kb);
    __builtin_amdgcn_s_barrier();
    MMA_Q(1, 1, b1);
    __builtin_amdgcn_s_barrier();              // P4 reads nothing: no wait

    // ---- Phase 4: stage Ah1(next), MFMA Q(1,0) (b0 still live)
    if (pf) STAGE_A(1, kb);
    __builtin_amdgcn_s_barrier();
    MMA_Q(1, 0, b0);
    if (pf) { WAITV(4); }                      // next tile P1: Ah0+Bh0 landed
    __builtin_amdgcn_s_barrier();
  }

  // C-write: 32 lanes x 4 B contiguous = 128-B segments per store instr.
#pragma unroll
  for (int fa = 0; fa < 4; fa++)
#pragma unroll
    for (int nf = 0; nf < 2; nf++)
#pragma unroll
      for (int reg = 0; reg < 16; reg++) {
        size_t row = bm + wm * 128 + fa * 32 +
                     (reg & 3) + 8 * (reg >> 2) + 4 * (lane >> 5);
        size_t col = bn + wn * 64 + nf * 32 + (lane & 31);
        C[row * OUTD + col] = acc[fa][nf][reg];
      }
#undef STAGE_A
#undef STAGE_B
#undef READ_A
#undef READ_B
#undef MMA_Q
}

extern "C" void kernel_launch(void* const* d_in, const int* in_sizes, int n_in,
                              void* d_out, int out_size, void* d_ws, size_t ws_size,
                              hipStream_t stream) {
  (void)in_sizes; (void)n_in; (void)out_size;
  const float* x    = (const float*)d_in[0];
  const float* iw   = (const float*)d_in[1];
  const float* bvec = (const float*)d_in[2];
  const float* proj = (const float*)d_in[3];
  const float* xr   = (const float*)d_in[4];
  const float* xi   = (const float*)d_in[5];
  float* out = (float*)d_out;

  char* ws = (char*)d_ws;
  size_t off = 0;
  auto take = [&](size_t bytes) {
    char* p = ws + off;
    off = (off + bytes + 255) & ~(size_t)255;
    return p;
  };
  unsigned short* F      = (unsigned short*)take((size_t)NROWS * KDIM * 2);  // 134 MB
  unsigned short* Wp     = (unsigned short*)take((size_t)OUTD * KDIM * 2);   // 2 MB
  unsigned short* projbf = (unsigned short*)take((size_t)NRF * DIMN * 2);    // 128 KB
  float* mg2 = (float*)take((size_t)NRF * 4);
  if (ws_size < off) return;

  const float  scaleC = sqrtf(1.f + 4.f * MCOEF);
  const double c2d    = 0.5 * exp(128.0 * log(1.0 + 4.0 * 0.001));
  const float  invSR  = 0.0625f;
  const float  sRw    = (float)(c2d * 0.0625);

  prep_rf<<<NRF, 64, 0, stream>>>(proj, projbf, mg2);
  fused_features<<<NROWS / 64 + OUTD / 64, 256, 0, stream>>>(
      x, iw, bvec, xr, xi, mg2, projbf, F, Wp, invSR, sRw, scaleC);
  gemm_bt<<<1024, 512, 0, stream>>>(F, Wp, out);
}